// Round 6
// baseline (299.292 us; speedup 1.0000x reference)
//
#include <hip/hip_runtime.h>

// SCVC: out[n,o,i,j] = sum_{c,d} x[n,c,i] y[n,d,j] Cr[o,c,d]
//                      + a[n,o,i] + b[n,o,j] + bias[o]
// a = dilated conv (k=2, pad=1, dil=2) of channel-tiled x, W_A folded over the
// tile-repeat; b likewise for y / W_B.
// N=32, IN1=IN2=4, OUT=128, DX=DY=128. All float32.
//
// Ledger: R0 base 266.4 | R1 clamp artifact 330 | R3 nt stores +7 (reverted) |
// R4 o-pair 264.7 (prologues hidden) | R5 per-wave-linear 263.1 (neutral).
// Fill evidence: 6.5 TB/s at ~10% occupancy (~3 waves/CU) via LONG grid-stride
// store streams. Last untested difference: our waves issued short 32-instr
// store bursts then drained; fill waves stream thousands.
//
// R6: stream-shaped kernel. 512 blocks (2/CU, 8 waves/CU), block = (n, 8-wide
// o-chunk). Weights for all 8 o's folded once; x/y conv taps + y row tile
// hoisted to registers once. Then 4 iterations of {phase1 -> barrier ->
// 32 dense 1KB wave-stores} = 128 back-to-back store instrs per wave
// (512 KB/block), store queue continuously primed; drain only at kernel end.

__global__ __launch_bounds__(256) void scvc_kernel(
    const float* __restrict__ x,     // [32,4,128]
    const float* __restrict__ y,     // [32,4,128]
    const float* __restrict__ C,     // [128,16]
    const float* __restrict__ WA,    // [128,16,2]
    const float* __restrict__ WB,    // [128,16,2]
    const float* __restrict__ bias,  // [128]
    float* __restrict__ out)         // [32,128,128,128]
{
    const int n     = blockIdx.x >> 4;   // 0..31
    const int chunk = blockIdx.x & 15;   // 0..15 -> o in [chunk*8, chunk*8+8)
    const int tid   = threadIdx.x;
    const int obase = chunk * 8;

    __shared__ float csh8[8][16];    // Cr[c*4+d] for the chunk's 8 o's
    __shared__ float wash8[8][8];    // folded W_A per o: [c*2+k]
    __shared__ float wbsh8[8][8];    // folded W_B per o: [c*2+k]
    __shared__ float t4[2][128][4];  // t4[oi][i][d] = sum_c x[c,i]*Cr[c,d]
    __shared__ float arow[2][128];
    __shared__ float bcol[2][128];   // includes bias

    const float* xb = x + n * 512;
    const float* yb = y + n * 512;

    // ---- phase 0 (once): fold weights for ALL 8 o's of the chunk ----
    if (tid < 128) {
        const int oo = tid >> 4, t = tid & 15;
        csh8[oo][t] = C[(obase + oo) * 16 + t];
    } else if (tid < 192) {
        const int idx = tid - 128;          // oo*8 + (c*2+k)
        const int oo = idx >> 3, w = idx & 7;
        const int c = w >> 1, k = w & 1;
        float s = 0.f;
        #pragma unroll
        for (int r = 0; r < 4; ++r) s += WA[(obase + oo) * 32 + (4 * r + c) * 2 + k];
        wash8[oo][w] = s;
    } else {
        const int idx = tid - 192;
        const int oo = idx >> 3, w = idx & 7;
        const int c = w >> 1, k = w & 1;
        float s = 0.f;
        #pragma unroll
        for (int r = 0; r < 4; ++r) s += WB[(obase + oo) * 32 + (4 * r + c) * 2 + k];
        wbsh8[oo][w] = s;
    }

    // ---- hoisted per-n register state (independent of o) ----
    float xv[4], xm[4], xp[4];   // valid for tid < 128 (row role)
    float ymv[4], ypv[4];        // valid for tid >= 128 (col role)
    if (tid < 128) {
        const int i = tid;
        #pragma unroll
        for (int c = 0; c < 4; ++c) {
            xv[c] = xb[c * 128 + i];
            xm[c] = (i > 0)   ? xb[c * 128 + i - 1] : 0.f;  // conv tap t-1
            xp[c] = (i < 127) ? xb[c * 128 + i + 1] : 0.f;  // conv tap t+1
        }
    } else {
        const int j = tid - 128;
        #pragma unroll
        for (int c = 0; c < 4; ++c) {
            ymv[c] = (j > 0)   ? yb[c * 128 + j - 1] : 0.f;
            ypv[c] = (j < 127) ? yb[c * 128 + j + 1] : 0.f;
        }
    }

    // phase-2 geometry + y row tile (all threads)
    const int wave = tid >> 6;          // 0..3
    const int lane = tid & 63;
    const int col4 = (lane & 31) * 4;   // 0,4,...,124
    const int half = lane >> 5;         // 0/1
    float yr[4][4];
    #pragma unroll
    for (int d = 0; d < 4; ++d) {
        const float4 v = *(const float4*)(yb + d * 128 + col4);
        yr[d][0] = v.x; yr[d][1] = v.y; yr[d][2] = v.z; yr[d][3] = v.w;
    }

    __syncthreads();

    // ---- 4 pipelined o-pair iterations: phase1 -> barrier -> 32 stores ----
    for (int p = 0; p < 4; ++p) {
        if (p) __syncthreads();          // protect t4/arow/bcol overwrite

        const int o0 = obase + 2 * p;    // pair {o0, o0+1}

        if (tid < 128) {
            const int i = tid;
            #pragma unroll
            for (int oi = 0; oi < 2; ++oi) {
                const int oo = 2 * p + oi;
                #pragma unroll
                for (int d = 0; d < 4; ++d) {
                    float s = 0.f;
                    #pragma unroll
                    for (int c = 0; c < 4; ++c) s += xv[c] * csh8[oo][c * 4 + d];
                    t4[oi][i][d] = s;
                }
                float a = 0.f;
                #pragma unroll
                for (int c = 0; c < 4; ++c)
                    a += xm[c] * wash8[oo][c * 2] + xp[c] * wash8[oo][c * 2 + 1];
                arow[oi][i] = a;
            }
        } else {
            const int j = tid - 128;
            #pragma unroll
            for (int oi = 0; oi < 2; ++oi) {
                const int oo = 2 * p + oi;
                float b = bias[o0 + oi];
                #pragma unroll
                for (int c = 0; c < 4; ++c)
                    b += ymv[c] * wbsh8[oo][c * 2] + ypv[c] * wbsh8[oo][c * 2 + 1];
                bcol[oi][j] = b;
            }
        }
        __syncthreads();

        // stores: wave w owns rows [32w,32w+32), dense 1KB lines, sequential.
        #pragma unroll
        for (int oi = 0; oi < 2; ++oi) {
            const float4 bv = *(const float4*)(&bcol[oi][col4]);
            float bj[4];
            bj[0] = bv.x; bj[1] = bv.y; bj[2] = bv.z; bj[3] = bv.w;

            float* op = out + (((long)(n * 128 + o0 + oi)) << 14) + col4;
            #pragma unroll
            for (int it = 0; it < 16; ++it) {
                const int i = wave * 32 + it * 2 + half;
                const float4 t = *(const float4*)(&t4[oi][i][0]);  // broadcast b128
                const float ai = arow[oi][i];
                float4 r;
                r.x = t.x * yr[0][0] + t.y * yr[1][0] + t.z * yr[2][0] + t.w * yr[3][0] + (ai + bj[0]);
                r.y = t.x * yr[0][1] + t.y * yr[1][1] + t.z * yr[2][1] + t.w * yr[3][1] + (ai + bj[1]);
                r.z = t.x * yr[0][2] + t.y * yr[1][2] + t.z * yr[2][2] + t.w * yr[3][2] + (ai + bj[2]);
                r.w = t.x * yr[0][3] + t.y * yr[1][3] + t.z * yr[2][3] + t.w * yr[3][3] + (ai + bj[3]);
                *(float4*)(op + i * 128) = r;   // fire-and-forget; drains at end
            }
        }
    }
}

extern "C" void kernel_launch(void* const* d_in, const int* in_sizes, int n_in,
                              void* d_out, int out_size, void* d_ws, size_t ws_size,
                              hipStream_t stream) {
    const float* x    = (const float*)d_in[0];
    const float* y    = (const float*)d_in[1];
    const float* C    = (const float*)d_in[2];
    const float* WA   = (const float*)d_in[3];
    const float* WB   = (const float*)d_in[4];
    const float* bias = (const float*)d_in[5];
    float* out = (float*)d_out;

    scvc_kernel<<<32 * 16, 256, 0, stream>>>(x, y, C, WA, WB, bias, out);
}